// Round 1
// 587.421 us; speedup vs baseline: 1.0618x; 1.0618x over previous
//
#include <hip/hip_runtime.h>
#include <math.h>

#define N_NODES 50000
#define N_EDGES 800000
#define D_IN    128
#define ED_IN   64
#define HU      128   // H*U
#define NH      4
#define UD      32

#define NPB 16   // nodes per block in qkvg kernel

typedef float fx4 __attribute__((ext_vector_type(4)));

static __device__ __forceinline__ unsigned short f2bf(float f) {
  unsigned u = __float_as_uint(f);
  unsigned r = (u + 0x7FFFu + ((u >> 16) & 1u)) >> 16;
  return (unsigned short)r;
}
static __device__ __forceinline__ float bf_lo(unsigned u) {
  return __uint_as_float(u << 16);
}
static __device__ __forceinline__ float bf_hi(unsigned u) {
  return __uint_as_float(u & 0xFFFF0000u);
}
// 8-element dot: fp32 a0|a1 against 8 bf16 packed in uint4
static __device__ __forceinline__ float dot8(float4 a0, float4 a1, uint4 kk) {
  return a0.x * bf_lo(kk.x) + a0.y * bf_hi(kk.x)
       + a0.z * bf_lo(kk.y) + a0.w * bf_hi(kk.y)
       + a1.x * bf_lo(kk.z) + a1.y * bf_hi(kk.z)
       + a1.z * bf_lo(kk.w) + a1.w * bf_hi(kk.w);
}

// K0: segment offsets from sorted src. off[n] = lower_bound(src, n); off[N] = E.
__global__ __launch_bounds__(256) void offsets_kernel(
    const int* __restrict__ src, int* __restrict__ off) {
  const int e = blockIdx.x * 256 + threadIdx.x;
  if (e >= N_EDGES) return;
  const int s = src[e];
  const int prev = (e == 0) ? -1 : src[e - 1];
  for (int n = prev + 1; n <= s; ++n) off[n] = e;
  if (e == N_EDGES - 1)
    for (int n = s + 1; n <= N_NODES; ++n) off[n] = N_EDGES;
}

// K1: fused q/k/v projections + g matrix, writing the interleaved kg layout:
//   kg (ushort): node stride 384; head h at +h*96: [32 x k bf16][64 x g bf16]
//   q fp32 (bq+be folded); v bf16 [n][128]
__global__ __launch_bounds__(128) void qkvg_kernel(
    const float* __restrict__ x,
    const float* __restrict__ Wq, const float* __restrict__ bq,
    const float* __restrict__ Wk, const float* __restrict__ bk,
    const float* __restrict__ Wv, const float* __restrict__ bv,
    const float* __restrict__ be, const float* __restrict__ We,
    float* __restrict__ q, unsigned short* __restrict__ kg,
    unsigned short* __restrict__ vbf) {
  const int base = blockIdx.x * NPB;
  const int t = threadIdx.x;
  __shared__ float xs[NPB][D_IN];
  for (int j = 0; j < NPB; ++j)
    xs[j][t] = x[(long)(base + j) * D_IN + t];
  __syncthreads();
  float aq[NPB], ak[NPB], av[NPB];
  const float bqt = bq[t] + be[t], bkt = bk[t], bvt = bv[t];
#pragma unroll
  for (int j = 0; j < NPB; ++j) { aq[j] = bqt; ak[j] = bkt; av[j] = bvt; }
  for (int i = 0; i < D_IN; ++i) {
    const float wq = Wq[i * HU + t];
    const float wk = Wk[i * HU + t];
    const float wv = Wv[i * HU + t];
#pragma unroll
    for (int j = 0; j < NPB; ++j) {
      const float xi = xs[j][i];
      aq[j] += xi * wq; ak[j] += xi * wk; av[j] += xi * wv;
    }
  }
  const int h = t >> 5, u = t & 31;
#pragma unroll
  for (int j = 0; j < NPB; ++j) {
    const long nn = base + j;
    q[nn * HU + t] = aq[j];
    vbf[nn * HU + t] = f2bf(av[j]);
    kg[nn * 384 + h * 96 + u] = f2bf(ak[j]);
  }
  __syncthreads();
#pragma unroll
  for (int j = 0; j < NPB; ++j) xs[j][t] = ak[j];  // reuse xs as k staging
  __syncthreads();
  for (int r = 0; r < 2; ++r) {
    const int o = t + 128 * r;      // output index in [0,256)
    const int oh = o >> 6, oi = o & 63;
    float acc[NPB];
#pragma unroll
    for (int j = 0; j < NPB; ++j) acc[j] = 0.f;
    for (int u2 = 0; u2 < 32; ++u2) {
      const float w = We[oi * HU + oh * 32 + u2];
#pragma unroll
      for (int j = 0; j < NPB; ++j) acc[j] += w * xs[j][oh * 32 + u2];
    }
#pragma unroll
    for (int j = 0; j < NPB; ++j)
      kg[(long)(base + j) * 384 + oh * 96 + 32 + oi] = f2bf(acc[j]);
  }
}

// K2: one thread per (edge, head); 64 edges per 256-thread block.
// scores[e,h] = q'[s,h,:]·k[d,h,:] + ef[e,:]·g[d,h,:]
// k+g read as ONE contiguous 192B record.
// MLP version: __launch_bounds__(256,2) lifts the 64-VGPR cap so ALL 20
// global loads (12x kg gather + 8x q) issue before any wait; ef staged
// PER-WAVE (wave w owns rows [16w,16w+16)) so no __syncthreads() and no
// vmcnt(0) drain — kg/q stay in flight across the LDS wait.
__global__ __launch_bounds__(256, 2) void score_kernel(
    const float* __restrict__ ef,
    const int* __restrict__ src, const int* __restrict__ dst,
    const float* __restrict__ q, const uint4* __restrict__ kg,
    float* __restrict__ scores) {
  __shared__ float efs[64][ED_IN + 1];
  const int t = threadIdx.x;
  const int w = t >> 6, l = t & 63;
  const long ebase = (long)blockIdx.x * 64;
  const int e = (int)(ebase + (t >> 2));
  const int h = t & 3;
  const int s = src[e], d = dst[e];

  // one contiguous 192B record: 4 uint4 of k + 8 uint4 of g — random gather,
  // longest latency, issue FIRST and all at once.
  const uint4* kgp = kg + (long)d * 48 + h * 12;
  const uint4 kk0 = kgp[0], kk1 = kgp[1], kk2 = kgp[2], kk3 = kgp[3];
  const uint4 g0 = kgp[4], g1 = kgp[5], g2 = kgp[6], g3 = kgp[7];
  const uint4 g4 = kgp[8], g5 = kgp[9], g6 = kgp[10], g7 = kgp[11];

  // per-wave ef staging: wave w stages exactly rows [16w, 16w+16) that its
  // own lanes read below. 4x 16B coalesced nontemporal loads per lane.
  const fx4* efb = (const fx4*)(ef + ebase * ED_IN);
#pragma unroll
  for (int r = 0; r < 4; ++r) {
    const int m = w * 256 + r * 64 + l;   // float4 index in block's [64][64]
    const fx4 vv = __builtin_nontemporal_load(efb + m);
    const int row = m >> 4, i0 = (m & 15) * 4;
    efs[row][i0] = vv.x; efs[row][i0 + 1] = vv.y;
    efs[row][i0 + 2] = vv.z; efs[row][i0 + 3] = vv.w;
  }

  // q gather: src is sorted -> L1/L2 hot; issue after the cold gathers.
  const float4* qp = (const float4*)(q + (long)s * HU + h * 32);
  const float4 q0 = qp[0], q1 = qp[1], q2 = qp[2], q3 = qp[3];
  const float4 q4 = qp[4], q5 = qp[5], q6 = qp[6], q7 = qp[7];

  float p = dot8(q0, q1, kk0) + dot8(q2, q3, kk1)
          + dot8(q4, q5, kk2) + dot8(q6, q7, kk3);

  // wave-synchronous: only this wave's own ds_writes must land; does NOT
  // drain vmcnt, so nothing else is forced to wait here.
  asm volatile("s_waitcnt lgkmcnt(0)" ::: "memory");

  const float* er = efs[t >> 2];
#define EFDOT(GC, c)                                                          \
  {                                                                           \
    const float4 a0 = make_float4(er[(c) * 8 + 0], er[(c) * 8 + 1],           \
                                  er[(c) * 8 + 2], er[(c) * 8 + 3]);          \
    const float4 a1 = make_float4(er[(c) * 8 + 4], er[(c) * 8 + 5],           \
                                  er[(c) * 8 + 6], er[(c) * 8 + 7]);          \
    p += dot8(a0, a1, GC);                                                    \
  }
  EFDOT(g0, 0) EFDOT(g1, 1) EFDOT(g2, 2) EFDOT(g3, 3)
  EFDOT(g4, 4) EFDOT(g5, 5) EFDOT(g6, 6) EFDOT(g7, 7)
#undef EFDOT

  __builtin_nontemporal_store(p, scores + (long)e * NH + h);
}

// K3: one WAVE per node (4 nodes per 256-thread block), barrier-free.
// Lane l: features 2l,2l+1 (head h=l>>4); softmax in 16-lane shuffle groups.
__global__ __launch_bounds__(256) void aggregate_kernel(
    const int* __restrict__ off, const int* __restrict__ dst,
    const float* __restrict__ scores, const unsigned* __restrict__ v2,
    const float* __restrict__ Wo, const float* __restrict__ bo,
    float* __restrict__ out) {
  const int wv = threadIdx.x >> 6, l = threadIdx.x & 63;
  const int n = blockIdx.x * 4 + wv;
  const int h = l >> 4, q16 = l & 15;
  __shared__ float att[4][HU];

  const int start = off[n], end = off[n + 1];
  float m = -INFINITY, lsum = 0.f, a0 = 0.f, a1 = 0.f;
  for (int cs = start; cs < end; cs += 16) {
    const int e = cs + q16;
    const bool live = (e < end);
    const float sc = live ? __builtin_nontemporal_load(scores + (long)e * NH + h)
                          : -INFINITY;
    const int dl = live ? dst[e] : 0;
    float mc = sc;
#pragma unroll
    for (int o = 8; o > 0; o >>= 1) mc = fmaxf(mc, __shfl_xor(mc, o, 16));
    const float nm = fmaxf(m, mc);          // finite: >=1 live edge per chunk
    const float corr = __expf(m - nm);      // 0 on first chunk
    const float w = __expf(sc - nm);        // 0 for dead lanes
    float ws = w;
#pragma unroll
    for (int o = 8; o > 0; o >>= 1) ws += __shfl_xor(ws, o, 16);
    lsum = lsum * corr + ws;
    a0 *= corr; a1 *= corr; m = nm;
    // fully unrolled: dead entries have w=0, dst=0 (harmless cached row-0 load)
#pragma unroll
    for (int j = 0; j < 16; ++j) {
      const float wj = __shfl(w, (l & 48) + j, 64);
      const int dj = __shfl(dl, (l & 48) + j, 64);
      const unsigned vr = v2[(long)dj * 64 + l];   // 256B coalesced row
      a0 += wj * bf_lo(vr);
      a1 += wj * bf_hi(vr);
    }
  }
  const float inv = (lsum > 0.f) ? 1.f / lsum : 0.f;
  att[wv][2 * l] = a0 * inv;
  att[wv][2 * l + 1] = a1 * inv;
  // wave-synchronous: same wave wrote these LDS entries, no barrier needed
  const int o = l & 31, half = l >> 5;
  float po = 0.f;
#pragma unroll
  for (int f = 0; f < 64; ++f)
    po += att[wv][half * 64 + f] * Wo[(half * 64 + f) * UD + o];
  po += __shfl_down(po, 32, 64);
  if (l < 32) out[(long)n * UD + l] = fmaxf(po + bo[l], 0.f);
}

extern "C" void kernel_launch(void* const* d_in, const int* in_sizes, int n_in,
                              void* d_out, int out_size, void* d_ws, size_t ws_size,
                              hipStream_t stream) {
  const float* x  = (const float*)d_in[0];
  const int*   ei = (const int*)d_in[1];
  const float* ef = (const float*)d_in[2];
  const float* Wq = (const float*)d_in[3];
  const float* bq = (const float*)d_in[4];
  const float* Wk = (const float*)d_in[5];
  const float* bk = (const float*)d_in[6];
  const float* Wv = (const float*)d_in[7];
  const float* bv = (const float*)d_in[8];
  const float* We = (const float*)d_in[9];
  const float* be = (const float*)d_in[10];
  const float* Wo = (const float*)d_in[11];
  const float* bo = (const float*)d_in[12];
  float* out = (float*)d_out;

  const int* src = ei;             // edge_index[0]
  const int* dst = ei + N_EDGES;   // edge_index[1]

  // ws: q fp32 [N*128] | kg ushort [N*384] | vbf ushort [N*128] | scores [E*4] | off
  float* q = (float*)d_ws;
  unsigned short* kg = (unsigned short*)(q + (long)N_NODES * HU);
  unsigned short* vbf = kg + (long)N_NODES * 384;
  float* scores = (float*)(vbf + (long)N_NODES * HU);
  int* off = (int*)(scores + (long)N_EDGES * NH);

  offsets_kernel<<<(N_EDGES + 255) / 256, 256, 0, stream>>>(src, off);
  qkvg_kernel<<<N_NODES / NPB, 128, 0, stream>>>(x, Wq, bq, Wk, bk, Wv, bv, be, We,
                                                 q, kg, vbf);
  score_kernel<<<N_EDGES / 64, 256, 0, stream>>>(ef, src, dst, q,
                                                 (const uint4*)kg, scores);
  aggregate_kernel<<<N_NODES / 4, 256, 0, stream>>>(off, dst, scores,
                                                    (const unsigned*)vbf, Wo, bo, out);
}

// Round 2
// 514.202 us; speedup vs baseline: 1.2130x; 1.1424x over previous
//
#include <hip/hip_runtime.h>
#include <math.h>

#define N_NODES 50000
#define N_EDGES 800000
#define D_IN    128
#define ED_IN   64
#define HU      128   // H*U
#define NH      4
#define UD      32

#define NPB 16   // nodes per block in qkv kernel

typedef float fx4 __attribute__((ext_vector_type(4)));
typedef short s16x8 __attribute__((ext_vector_type(8)));
typedef float f32x4 __attribute__((ext_vector_type(4)));

static __device__ __forceinline__ unsigned short f2bf(float f) {
  unsigned u = __float_as_uint(f);
  unsigned r = (u + 0x7FFFu + ((u >> 16) & 1u)) >> 16;
  return (unsigned short)r;
}
static __device__ __forceinline__ float bf_lo(unsigned u) {
  return __uint_as_float(u << 16);
}
static __device__ __forceinline__ float bf_hi(unsigned u) {
  return __uint_as_float(u & 0xFFFF0000u);
}
// 8-element dot: fp32 a0|a1 against 8 bf16 packed in uint4
static __device__ __forceinline__ float dot8(float4 a0, float4 a1, uint4 kk) {
  return a0.x * bf_lo(kk.x) + a0.y * bf_hi(kk.x)
       + a0.z * bf_lo(kk.y) + a0.w * bf_hi(kk.y)
       + a1.x * bf_lo(kk.z) + a1.y * bf_hi(kk.z)
       + a1.z * bf_lo(kk.w) + a1.w * bf_hi(kk.w);
}
static __device__ __forceinline__ float4 f4add(float4 a, float4 b) {
  return make_float4(a.x + b.x, a.y + b.y, a.z + b.z, a.w + b.w);
}

// K0: segment offsets from sorted src. off[n] = lower_bound(src, n); off[N] = E.
__global__ __launch_bounds__(256) void offsets_kernel(
    const int* __restrict__ src, int* __restrict__ off) {
  const int e = blockIdx.x * 256 + threadIdx.x;
  if (e >= N_EDGES) return;
  const int s = src[e];
  const int prev = (e == 0) ? -1 : src[e - 1];
  for (int n = prev + 1; n <= s; ++n) off[n] = e;
  if (e == N_EDGES - 1)
    for (int n = s + 1; n <= N_NODES; ++n) off[n] = N_EDGES;
}

// K0b: pack We (fp32 [64][128]) into bf16 MFMA B-fragments for 16x16x32:
// frag f = nt*2+kh, lane l holds B[k][n] for n = nt*16+(l&15),
// k = kh*32 + (l>>4)*8 + j  (j = 0..7, lane-contiguous 16B record).
__global__ __launch_bounds__(256) void wepack_kernel(
    const float* __restrict__ We, unsigned short* __restrict__ wf) {
  const int fl = blockIdx.x * 256 + threadIdx.x;   // 16 frags * 64 lanes
  if (fl >= 16 * 64) return;
  const int f = fl >> 6, lane = fl & 63;
  const int nt = f >> 1, kh = f & 1;
  const int n = nt * 16 + (lane & 15);
  const int kbase = kh * 32 + (lane >> 4) * 8;
#pragma unroll
  for (int j = 0; j < 8; ++j)
    wf[fl * 8 + j] = f2bf(We[(kbase + j) * HU + n]);
}

// K1: fused q/k/v projections. q fp32 (bq+be folded); k,v bf16 [n][128].
__global__ __launch_bounds__(128) void qkv_kernel(
    const float* __restrict__ x,
    const float* __restrict__ Wq, const float* __restrict__ bq,
    const float* __restrict__ Wk, const float* __restrict__ bk,
    const float* __restrict__ Wv, const float* __restrict__ bv,
    const float* __restrict__ be,
    float* __restrict__ q, unsigned short* __restrict__ kbf,
    unsigned short* __restrict__ vbf) {
  const int base = blockIdx.x * NPB;
  const int t = threadIdx.x;
  __shared__ float xs[NPB][D_IN];
  for (int j = 0; j < NPB; ++j)
    xs[j][t] = x[(long)(base + j) * D_IN + t];
  __syncthreads();
  float aq[NPB], ak[NPB], av[NPB];
  const float bqt = bq[t] + be[t], bkt = bk[t], bvt = bv[t];
#pragma unroll
  for (int j = 0; j < NPB; ++j) { aq[j] = bqt; ak[j] = bkt; av[j] = bvt; }
  for (int i = 0; i < D_IN; ++i) {
    const float wq = Wq[i * HU + t];
    const float wk = Wk[i * HU + t];
    const float wv = Wv[i * HU + t];
#pragma unroll
    for (int j = 0; j < NPB; ++j) {
      const float xi = xs[j][i];
      aq[j] += xi * wq; ak[j] += xi * wk; av[j] += xi * wv;
    }
  }
#pragma unroll
  for (int j = 0; j < NPB; ++j) {
    const long nn = base + j;
    q[nn * HU + t] = aq[j];
    kbf[nn * HU + t] = f2bf(ak[j]);
    vbf[nn * HU + t] = f2bf(av[j]);
  }
}

// K2: 64 edges per 256-thread block.
//   eh[64x128] = bf16(ef tile) @ bf16(We) via MFMA 16x16x32 (wave w owns
//   edge rows [16w,16w+16), A loaded straight from global, B from L1-hot
//   pre-packed fragments), redistributed through XOR-swizzled LDS.
//   score[e,h] = (q[s,h,:] + eh[e,h,:]) . k[d,h,:]   — only k (64B/thread)
//   is randomly gathered now (256B/edge vs 768B/edge before).
__global__ __launch_bounds__(256, 2) void score_kernel(
    const float* __restrict__ ef,
    const int* __restrict__ src, const int* __restrict__ dst,
    const float* __restrict__ q, const uint4* __restrict__ kbf,
    const s16x8* __restrict__ wf,
    float* __restrict__ scores) {
  __shared__ __align__(16) float ehs[64 * 128];   // 32 KB, swizzled rows
  const int t = threadIdx.x;
  const int w = t >> 6, l = t & 63;
  const long ebase = (long)blockIdx.x * 64;
  const int e = (int)(ebase + (t >> 2));
  const int h = t & 3;
  const int s = src[e], d = dst[e];

  // cold random gather first: k record (64B) — consumed last, longest shadow
  const uint4* kp = kbf + (long)d * 16 + h * 4;
  const uint4 k0 = kp[0], k1 = kp[1], k2 = kp[2], k3 = kp[3];

  // q row (sorted src -> cache-hot)
  const float4* qp = (const float4*)(q + (long)s * HU + h * 32);
  const float4 q0 = qp[0], q1 = qp[1], q2 = qp[2], q3 = qp[3];
  const float4 q4 = qp[4], q5 = qp[5], q6 = qp[6], q7 = qp[7];

  // A operand: lane l holds ef[arow][k], k = kh*32 + (l>>4)*8 + j
  const int arow = (int)(ebase + w * 16 + (l & 15));
  const fx4* ap = (const fx4*)(ef + (long)arow * ED_IN + (l >> 4) * 8);
  const fx4 a00 = __builtin_nontemporal_load(ap);
  const fx4 a01 = __builtin_nontemporal_load(ap + 1);
  const fx4 a10 = __builtin_nontemporal_load(ap + 8);
  const fx4 a11 = __builtin_nontemporal_load(ap + 9);
  s16x8 A0, A1;
  A0[0] = (short)f2bf(a00[0]); A0[1] = (short)f2bf(a00[1]);
  A0[2] = (short)f2bf(a00[2]); A0[3] = (short)f2bf(a00[3]);
  A0[4] = (short)f2bf(a01[0]); A0[5] = (short)f2bf(a01[1]);
  A0[6] = (short)f2bf(a01[2]); A0[7] = (short)f2bf(a01[3]);
  A1[0] = (short)f2bf(a10[0]); A1[1] = (short)f2bf(a10[1]);
  A1[2] = (short)f2bf(a10[2]); A1[3] = (short)f2bf(a10[3]);
  A1[4] = (short)f2bf(a11[0]); A1[5] = (short)f2bf(a11[1]);
  A1[6] = (short)f2bf(a11[2]); A1[7] = (short)f2bf(a11[3]);

  f32x4 acc[8];
#pragma unroll
  for (int nt = 0; nt < 8; ++nt) acc[nt] = (f32x4){0.f, 0.f, 0.f, 0.f};
#pragma unroll
  for (int nt = 0; nt < 8; ++nt) {
    const s16x8 B0 = wf[(nt * 2 + 0) * 64 + l];
    const s16x8 B1 = wf[(nt * 2 + 1) * 64 + l];
    acc[nt] = __builtin_amdgcn_mfma_f32_16x16x32_bf16(A0, B0, acc[nt], 0, 0, 0);
    acc[nt] = __builtin_amdgcn_mfma_f32_16x16x32_bf16(A1, B1, acc[nt], 0, 0, 0);
  }

  // scatter C to LDS: row m = w*16 + (l>>4)*4 + r, col n = nt*16 + (l&15)
  // swizzle byte-in-row ^= (m&7)<<4  -> verified even bank spread
  {
    const int nb = l & 15;
    const int mb = w * 16 + (l >> 4) * 4;
#pragma unroll
    for (int nt = 0; nt < 8; ++nt) {
#pragma unroll
      for (int r = 0; r < 4; ++r) {
        const int m = mb + r;
        const int b = (nt * 16 + nb) * 4;
        ehs[(m * 512 + (b ^ ((m & 7) << 4))) >> 2] = acc[nt][r];
      }
    }
  }
  __syncthreads();

  // score phase: thread (edge e_rel = t>>2, head h)
  const int er = t >> 2;
  const int swz = (er & 7) << 4;
  const char* ehp = (const char*)ehs + er * 512;
#define EHV(i) (*(const float4*)(ehp + (((h * 128) + (i) * 16) ^ swz)))
  const float4 e0 = EHV(0), e1 = EHV(1), e2 = EHV(2), e3 = EHV(3);
  const float4 e4 = EHV(4), e5 = EHV(5), e6 = EHV(6), e7 = EHV(7);
#undef EHV
  const float p = dot8(f4add(q0, e0), f4add(q1, e1), k0)
                + dot8(f4add(q2, e2), f4add(q3, e3), k1)
                + dot8(f4add(q4, e4), f4add(q5, e5), k2)
                + dot8(f4add(q6, e6), f4add(q7, e7), k3);
  __builtin_nontemporal_store(p, scores + (long)e * NH + h);
}

// K3: one WAVE per node (4 nodes per 256-thread block), barrier-free.
// Lane l: features 2l,2l+1 (head h=l>>4); softmax in 16-lane shuffle groups.
__global__ __launch_bounds__(256) void aggregate_kernel(
    const int* __restrict__ off, const int* __restrict__ dst,
    const float* __restrict__ scores, const unsigned* __restrict__ v2,
    const float* __restrict__ Wo, const float* __restrict__ bo,
    float* __restrict__ out) {
  const int wv = threadIdx.x >> 6, l = threadIdx.x & 63;
  const int n = blockIdx.x * 4 + wv;
  const int h = l >> 4, q16 = l & 15;
  __shared__ float att[4][HU];

  const int start = off[n], end = off[n + 1];
  float m = -INFINITY, lsum = 0.f, a0 = 0.f, a1 = 0.f;
  for (int cs = start; cs < end; cs += 16) {
    const int e = cs + q16;
    const bool live = (e < end);
    const float sc = live ? __builtin_nontemporal_load(scores + (long)e * NH + h)
                          : -INFINITY;
    const int dl = live ? dst[e] : 0;
    float mc = sc;
#pragma unroll
    for (int o = 8; o > 0; o >>= 1) mc = fmaxf(mc, __shfl_xor(mc, o, 16));
    const float nm = fmaxf(m, mc);          // finite: >=1 live edge per chunk
    const float corr = __expf(m - nm);      // 0 on first chunk
    const float w = __expf(sc - nm);        // 0 for dead lanes
    float ws = w;
#pragma unroll
    for (int o = 8; o > 0; o >>= 1) ws += __shfl_xor(ws, o, 16);
    lsum = lsum * corr + ws;
    a0 *= corr; a1 *= corr; m = nm;
    // fully unrolled: dead entries have w=0, dst=0 (harmless cached row-0 load)
#pragma unroll
    for (int j = 0; j < 16; ++j) {
      const float wj = __shfl(w, (l & 48) + j, 64);
      const int dj = __shfl(dl, (l & 48) + j, 64);
      const unsigned vr = v2[(long)dj * 64 + l];   // 256B coalesced row
      a0 += wj * bf_lo(vr);
      a1 += wj * bf_hi(vr);
    }
  }
  const float inv = (lsum > 0.f) ? 1.f / lsum : 0.f;
  att[wv][2 * l] = a0 * inv;
  att[wv][2 * l + 1] = a1 * inv;
  // wave-synchronous: same wave wrote these LDS entries, no barrier needed
  const int o = l & 31, half = l >> 5;
  float po = 0.f;
#pragma unroll
  for (int f = 0; f < 64; ++f)
    po += att[wv][half * 64 + f] * Wo[(half * 64 + f) * UD + o];
  po += __shfl_down(po, 32, 64);
  if (l < 32) out[(long)n * UD + l] = fmaxf(po + bo[l], 0.f);
}

extern "C" void kernel_launch(void* const* d_in, const int* in_sizes, int n_in,
                              void* d_out, int out_size, void* d_ws, size_t ws_size,
                              hipStream_t stream) {
  const float* x  = (const float*)d_in[0];
  const int*   ei = (const int*)d_in[1];
  const float* ef = (const float*)d_in[2];
  const float* Wq = (const float*)d_in[3];
  const float* bq = (const float*)d_in[4];
  const float* Wk = (const float*)d_in[5];
  const float* bk = (const float*)d_in[6];
  const float* Wv = (const float*)d_in[7];
  const float* bv = (const float*)d_in[8];
  const float* We = (const float*)d_in[9];
  const float* be = (const float*)d_in[10];
  const float* Wo = (const float*)d_in[11];
  const float* bo = (const float*)d_in[12];
  float* out = (float*)d_out;

  const int* src = ei;             // edge_index[0]
  const int* dst = ei + N_EDGES;   // edge_index[1]

  // ws: q fp32 [N*128] | kbf [N*128] | vbf [N*128] | scores [E*4] | off | wf
  float* q = (float*)d_ws;
  unsigned short* kbf = (unsigned short*)(q + (long)N_NODES * HU);
  unsigned short* vbf = kbf + (long)N_NODES * HU;
  float* scores = (float*)(vbf + (long)N_NODES * HU);
  int* off = (int*)(scores + (long)N_EDGES * NH);
  unsigned short* wf = (unsigned short*)(((uintptr_t)(off + N_NODES + 1) + 15)
                                         & ~(uintptr_t)15);

  offsets_kernel<<<(N_EDGES + 255) / 256, 256, 0, stream>>>(src, off);
  wepack_kernel<<<4, 256, 0, stream>>>(We, wf);
  qkv_kernel<<<N_NODES / NPB, 128, 0, stream>>>(x, Wq, bq, Wk, bk, Wv, bv, be,
                                                q, kbf, vbf);
  score_kernel<<<N_EDGES / 64, 256, 0, stream>>>(ef, src, dst, q,
                                                 (const uint4*)kbf,
                                                 (const s16x8*)wf, scores);
  aggregate_kernel<<<N_NODES / 4, 256, 0, stream>>>(off, dst, scores,
                                                    (const unsigned*)vbf, Wo, bo, out);
}

// Round 3
// 513.423 us; speedup vs baseline: 1.2148x; 1.0015x over previous
//
#include <hip/hip_runtime.h>
#include <math.h>

#define N_NODES 50000
#define N_EDGES 800000
#define D_IN    128
#define ED_IN   64
#define HU      128   // H*U
#define NH      4
#define UD      32

#define NPB 16   // nodes per block in qkv kernel

typedef float fx4 __attribute__((ext_vector_type(4)));
typedef short s16x8 __attribute__((ext_vector_type(8)));
typedef float f32x4 __attribute__((ext_vector_type(4)));

static __device__ __forceinline__ unsigned short f2bf(float f) {
  unsigned u = __float_as_uint(f);
  unsigned r = (u + 0x7FFFu + ((u >> 16) & 1u)) >> 16;
  return (unsigned short)r;
}
static __device__ __forceinline__ float bf_lo(unsigned u) {
  return __uint_as_float(u << 16);
}
static __device__ __forceinline__ float bf_hi(unsigned u) {
  return __uint_as_float(u & 0xFFFF0000u);
}
// 8-element dot: fp32 a0|a1 against 8 bf16 packed in uint4
static __device__ __forceinline__ float dot8(float4 a0, float4 a1, uint4 kk) {
  return a0.x * bf_lo(kk.x) + a0.y * bf_hi(kk.x)
       + a0.z * bf_lo(kk.y) + a0.w * bf_hi(kk.y)
       + a1.x * bf_lo(kk.z) + a1.y * bf_hi(kk.z)
       + a1.z * bf_lo(kk.w) + a1.w * bf_hi(kk.w);
}
static __device__ __forceinline__ float4 f4add(float4 a, float4 b) {
  return make_float4(a.x + b.x, a.y + b.y, a.z + b.z, a.w + b.w);
}

// K0: segment offsets from sorted src. off[n] = lower_bound(src, n); off[N] = E.
__global__ __launch_bounds__(256) void offsets_kernel(
    const int* __restrict__ src, int* __restrict__ off) {
  const int e = blockIdx.x * 256 + threadIdx.x;
  if (e >= N_EDGES) return;
  const int s = src[e];
  const int prev = (e == 0) ? -1 : src[e - 1];
  for (int n = prev + 1; n <= s; ++n) off[n] = e;
  if (e == N_EDGES - 1)
    for (int n = s + 1; n <= N_NODES; ++n) off[n] = N_EDGES;
}

// K0b: pack We (fp32 [64][128]) into bf16 MFMA B-fragments for 16x16x32:
// frag f = nt*2+kh, lane l holds B[k][n] for n = nt*16+(l&15),
// k = kh*32 + (l>>4)*8 + j  (j = 0..7, lane-contiguous 16B record).
__global__ __launch_bounds__(256) void wepack_kernel(
    const float* __restrict__ We, unsigned short* __restrict__ wf) {
  const int fl = blockIdx.x * 256 + threadIdx.x;   // 16 frags * 64 lanes
  if (fl >= 16 * 64) return;
  const int f = fl >> 6, lane = fl & 63;
  const int nt = f >> 1, kh = f & 1;
  const int n = nt * 16 + (lane & 15);
  const int kbase = kh * 32 + (lane >> 4) * 8;
#pragma unroll
  for (int j = 0; j < 8; ++j)
    wf[fl * 8 + j] = f2bf(We[(kbase + j) * HU + n]);
}

// K1: fused q/k/v projections. q fp32 (bq+be folded); k,v bf16 [n][128].
__global__ __launch_bounds__(128) void qkv_kernel(
    const float* __restrict__ x,
    const float* __restrict__ Wq, const float* __restrict__ bq,
    const float* __restrict__ Wk, const float* __restrict__ bk,
    const float* __restrict__ Wv, const float* __restrict__ bv,
    const float* __restrict__ be,
    float* __restrict__ q, unsigned short* __restrict__ kbf,
    unsigned short* __restrict__ vbf) {
  const int base = blockIdx.x * NPB;
  const int t = threadIdx.x;
  __shared__ float xs[NPB][D_IN];
  for (int j = 0; j < NPB; ++j)
    xs[j][t] = x[(long)(base + j) * D_IN + t];
  __syncthreads();
  float aq[NPB], ak[NPB], av[NPB];
  const float bqt = bq[t] + be[t], bkt = bk[t], bvt = bv[t];
#pragma unroll
  for (int j = 0; j < NPB; ++j) { aq[j] = bqt; ak[j] = bkt; av[j] = bvt; }
  for (int i = 0; i < D_IN; ++i) {
    const float wq = Wq[i * HU + t];
    const float wk = Wk[i * HU + t];
    const float wv = Wv[i * HU + t];
#pragma unroll
    for (int j = 0; j < NPB; ++j) {
      const float xi = xs[j][i];
      aq[j] += xi * wq; ak[j] += xi * wk; av[j] += xi * wv;
    }
  }
#pragma unroll
  for (int j = 0; j < NPB; ++j) {
    const long nn = base + j;
    q[nn * HU + t] = aq[j];
    kbf[nn * HU + t] = f2bf(ak[j]);
    vbf[nn * HU + t] = f2bf(av[j]);
  }
}

// K2: 64 edges per 256-thread block, BARRIER-FREE.
//   Wave w computes eh rows [16w,16w+16) = exactly the rows its own score
//   phase consumes, so the LDS redistribution is intra-wave: a wave-local
//   s_waitcnt lgkmcnt(0) replaces __syncthreads(). Waves never couple; the
//   k-gather (vmcnt) stays in flight across the LDS wait.
//   score[e,h] = (q[s,h,:] + eh[e,h,:]) . k[d,h,:]
__global__ __launch_bounds__(256, 2) void score_kernel(
    const float* __restrict__ ef,
    const int* __restrict__ src, const int* __restrict__ dst,
    const float* __restrict__ q, const uint4* __restrict__ kbf,
    const s16x8* __restrict__ wf,
    float* __restrict__ scores) {
  __shared__ __align__(16) float ehs[64 * 128];   // 32 KB, swizzled rows
  const int t = threadIdx.x;
  const int w = t >> 6, l = t & 63;
  const long ebase = (long)blockIdx.x * 64;
  const int e = (int)(ebase + (t >> 2));
  const int h = t & 3;
  const int s = src[e], d = dst[e];

  // cold random gather first: k record (64B) — consumed last, longest shadow
  const uint4* kp = kbf + (long)d * 16 + h * 4;
  const uint4 k0 = kp[0], k1 = kp[1], k2 = kp[2], k3 = kp[3];

  // q row (sorted src -> cache-hot)
  const float4* qp = (const float4*)(q + (long)s * HU + h * 32);
  const float4 q0 = qp[0], q1 = qp[1], q2 = qp[2], q3 = qp[3];
  const float4 q4 = qp[4], q5 = qp[5], q6 = qp[6], q7 = qp[7];

  // A operand: lane l holds ef[arow][k], k = kh*32 + (l>>4)*8 + j
  const int arow = (int)(ebase + w * 16 + (l & 15));
  const fx4* ap = (const fx4*)(ef + (long)arow * ED_IN + (l >> 4) * 8);
  const fx4 a00 = __builtin_nontemporal_load(ap);
  const fx4 a01 = __builtin_nontemporal_load(ap + 1);
  const fx4 a10 = __builtin_nontemporal_load(ap + 8);
  const fx4 a11 = __builtin_nontemporal_load(ap + 9);
  s16x8 A0, A1;
  A0[0] = (short)f2bf(a00[0]); A0[1] = (short)f2bf(a00[1]);
  A0[2] = (short)f2bf(a00[2]); A0[3] = (short)f2bf(a00[3]);
  A0[4] = (short)f2bf(a01[0]); A0[5] = (short)f2bf(a01[1]);
  A0[6] = (short)f2bf(a01[2]); A0[7] = (short)f2bf(a01[3]);
  A1[0] = (short)f2bf(a10[0]); A1[1] = (short)f2bf(a10[1]);
  A1[2] = (short)f2bf(a10[2]); A1[3] = (short)f2bf(a10[3]);
  A1[4] = (short)f2bf(a11[0]); A1[5] = (short)f2bf(a11[1]);
  A1[6] = (short)f2bf(a11[2]); A1[7] = (short)f2bf(a11[3]);

  f32x4 acc[8];
#pragma unroll
  for (int nt = 0; nt < 8; ++nt) acc[nt] = (f32x4){0.f, 0.f, 0.f, 0.f};
#pragma unroll
  for (int nt = 0; nt < 8; ++nt) {
    const s16x8 B0 = wf[(nt * 2 + 0) * 64 + l];
    const s16x8 B1 = wf[(nt * 2 + 1) * 64 + l];
    acc[nt] = __builtin_amdgcn_mfma_f32_16x16x32_bf16(A0, B0, acc[nt], 0, 0, 0);
    acc[nt] = __builtin_amdgcn_mfma_f32_16x16x32_bf16(A1, B1, acc[nt], 0, 0, 0);
  }

  // scatter C to LDS: row m = w*16 + (l>>4)*4 + r, col n = nt*16 + (l&15)
  // swizzle byte-in-row ^= (m&7)<<4  -> verified even bank spread
  {
    const int nb = l & 15;
    const int mb = w * 16 + (l >> 4) * 4;
#pragma unroll
    for (int nt = 0; nt < 8; ++nt) {
#pragma unroll
      for (int r = 0; r < 4; ++r) {
        const int m = mb + r;
        const int b = (nt * 16 + nb) * 4;
        ehs[(m * 512 + (b ^ ((m & 7) << 4))) >> 2] = acc[nt][r];
      }
    }
  }
  // wave-local: this wave's ds_writes cover exactly the rows it reads below.
  // Does NOT touch vmcnt — k loads stay in flight. sched_barrier pins order.
  asm volatile("s_waitcnt lgkmcnt(0)" ::: "memory");
  __builtin_amdgcn_sched_barrier(0);

  // score phase: thread (edge e_rel = t>>2, head h); rows [16w,16w+16) only
  const int er = t >> 2;
  const int swz = (er & 7) << 4;
  const char* ehp = (const char*)ehs + er * 512;
#define EHV(i) (*(const float4*)(ehp + (((h * 128) + (i) * 16) ^ swz)))
  const float4 e0 = EHV(0), e1 = EHV(1), e2 = EHV(2), e3 = EHV(3);
  const float4 e4 = EHV(4), e5 = EHV(5), e6 = EHV(6), e7 = EHV(7);
#undef EHV
  const float p = dot8(f4add(q0, e0), f4add(q1, e1), k0)
                + dot8(f4add(q2, e2), f4add(q3, e3), k1)
                + dot8(f4add(q4, e4), f4add(q5, e5), k2)
                + dot8(f4add(q6, e6), f4add(q7, e7), k3);
  __builtin_nontemporal_store(p, scores + (long)e * NH + h);
}

// K3: one WAVE per node (4 nodes per 256-thread block), barrier-free.
// Lane l: features 2l,2l+1 (head h=l>>4); softmax in 16-lane shuffle groups.
__global__ __launch_bounds__(256) void aggregate_kernel(
    const int* __restrict__ off, const int* __restrict__ dst,
    const float* __restrict__ scores, const unsigned* __restrict__ v2,
    const float* __restrict__ Wo, const float* __restrict__ bo,
    float* __restrict__ out) {
  const int wv = threadIdx.x >> 6, l = threadIdx.x & 63;
  const int n = blockIdx.x * 4 + wv;
  const int h = l >> 4, q16 = l & 15;
  __shared__ float att[4][HU];

  const int start = off[n], end = off[n + 1];
  float m = -INFINITY, lsum = 0.f, a0 = 0.f, a1 = 0.f;
  for (int cs = start; cs < end; cs += 16) {
    const int e = cs + q16;
    const bool live = (e < end);
    const float sc = live ? __builtin_nontemporal_load(scores + (long)e * NH + h)
                          : -INFINITY;
    const int dl = live ? dst[e] : 0;
    float mc = sc;
#pragma unroll
    for (int o = 8; o > 0; o >>= 1) mc = fmaxf(mc, __shfl_xor(mc, o, 16));
    const float nm = fmaxf(m, mc);          // finite: >=1 live edge per chunk
    const float corr = __expf(m - nm);      // 0 on first chunk
    const float w = __expf(sc - nm);        // 0 for dead lanes
    float ws = w;
#pragma unroll
    for (int o = 8; o > 0; o >>= 1) ws += __shfl_xor(ws, o, 16);
    lsum = lsum * corr + ws;
    a0 *= corr; a1 *= corr; m = nm;
    // fully unrolled: dead entries have w=0, dst=0 (harmless cached row-0 load)
#pragma unroll
    for (int j = 0; j < 16; ++j) {
      const float wj = __shfl(w, (l & 48) + j, 64);
      const int dj = __shfl(dl, (l & 48) + j, 64);
      const unsigned vr = v2[(long)dj * 64 + l];   // 256B coalesced row
      a0 += wj * bf_lo(vr);
      a1 += wj * bf_hi(vr);
    }
  }
  const float inv = (lsum > 0.f) ? 1.f / lsum : 0.f;
  att[wv][2 * l] = a0 * inv;
  att[wv][2 * l + 1] = a1 * inv;
  // wave-synchronous: same wave wrote these LDS entries, no barrier needed
  const int o = l & 31, half = l >> 5;
  float po = 0.f;
#pragma unroll
  for (int f = 0; f < 64; ++f)
    po += att[wv][half * 64 + f] * Wo[(half * 64 + f) * UD + o];
  po += __shfl_down(po, 32, 64);
  if (l < 32) out[(long)n * UD + l] = fmaxf(po + bo[l], 0.f);
}

extern "C" void kernel_launch(void* const* d_in, const int* in_sizes, int n_in,
                              void* d_out, int out_size, void* d_ws, size_t ws_size,
                              hipStream_t stream) {
  const float* x  = (const float*)d_in[0];
  const int*   ei = (const int*)d_in[1];
  const float* ef = (const float*)d_in[2];
  const float* Wq = (const float*)d_in[3];
  const float* bq = (const float*)d_in[4];
  const float* Wk = (const float*)d_in[5];
  const float* bk = (const float*)d_in[6];
  const float* Wv = (const float*)d_in[7];
  const float* bv = (const float*)d_in[8];
  const float* We = (const float*)d_in[9];
  const float* be = (const float*)d_in[10];
  const float* Wo = (const float*)d_in[11];
  const float* bo = (const float*)d_in[12];
  float* out = (float*)d_out;

  const int* src = ei;             // edge_index[0]
  const int* dst = ei + N_EDGES;   // edge_index[1]

  // ws: q fp32 [N*128] | kbf [N*128] | vbf [N*128] | scores [E*4] | off | wf
  float* q = (float*)d_ws;
  unsigned short* kbf = (unsigned short*)(q + (long)N_NODES * HU);
  unsigned short* vbf = kbf + (long)N_NODES * HU;
  float* scores = (float*)(vbf + (long)N_NODES * HU);
  int* off = (int*)(scores + (long)N_EDGES * NH);
  unsigned short* wf = (unsigned short*)(((uintptr_t)(off + N_NODES + 1) + 15)
                                         & ~(uintptr_t)15);

  offsets_kernel<<<(N_EDGES + 255) / 256, 256, 0, stream>>>(src, off);
  wepack_kernel<<<4, 256, 0, stream>>>(We, wf);
  qkv_kernel<<<N_NODES / NPB, 128, 0, stream>>>(x, Wq, bq, Wk, bk, Wv, bv, be,
                                                q, kbf, vbf);
  score_kernel<<<N_EDGES / 64, 256, 0, stream>>>(ef, src, dst, q,
                                                 (const uint4*)kbf,
                                                 (const s16x8*)wf, scores);
  aggregate_kernel<<<N_NODES / 4, 256, 0, stream>>>(off, dst, scores,
                                                    (const unsigned*)vbf, Wo, bo, out);
}

// Round 4
// 493.627 us; speedup vs baseline: 1.2636x; 1.0401x over previous
//
#include <hip/hip_runtime.h>
#include <math.h>

#define N_NODES 50000
#define N_EDGES 800000
#define D_IN    128
#define ED_IN   64
#define HU      128   // H*U
#define NH      4
#define UD      32

#define NPB 16   // nodes per block in qkv kernel

typedef float fx4 __attribute__((ext_vector_type(4)));
typedef short s16x8 __attribute__((ext_vector_type(8)));
typedef float f32x4 __attribute__((ext_vector_type(4)));

static __device__ __forceinline__ unsigned short f2bf(float f) {
  unsigned u = __float_as_uint(f);
  unsigned r = (u + 0x7FFFu + ((u >> 16) & 1u)) >> 16;
  return (unsigned short)r;
}
static __device__ __forceinline__ float bf_lo(unsigned u) {
  return __uint_as_float(u << 16);
}
static __device__ __forceinline__ float bf_hi(unsigned u) {
  return __uint_as_float(u & 0xFFFF0000u);
}
// 8-element dot: fp32 a0|a1 against 8 bf16 packed in uint4
static __device__ __forceinline__ float dot8(float4 a0, float4 a1, uint4 kk) {
  return a0.x * bf_lo(kk.x) + a0.y * bf_hi(kk.x)
       + a0.z * bf_lo(kk.y) + a0.w * bf_hi(kk.y)
       + a1.x * bf_lo(kk.z) + a1.y * bf_hi(kk.z)
       + a1.z * bf_lo(kk.w) + a1.w * bf_hi(kk.w);
}
static __device__ __forceinline__ float4 f4add(float4 a, float4 b) {
  return make_float4(a.x + b.x, a.y + b.y, a.z + b.z, a.w + b.w);
}

// K0: segment offsets from sorted src. off[n] = lower_bound(src, n); off[N] = E.
__global__ __launch_bounds__(256) void offsets_kernel(
    const int* __restrict__ src, int* __restrict__ off) {
  const int e = blockIdx.x * 256 + threadIdx.x;
  if (e >= N_EDGES) return;
  const int s = src[e];
  const int prev = (e == 0) ? -1 : src[e - 1];
  for (int n = prev + 1; n <= s; ++n) off[n] = e;
  if (e == N_EDGES - 1)
    for (int n = s + 1; n <= N_NODES; ++n) off[n] = N_EDGES;
}

// K0b: pack We (fp32 [64][128]) into bf16 MFMA B-fragments for 16x16x32:
// frag f = nt*2+kh, lane l holds B[k][n] for n = nt*16+(l&15),
// k = kh*32 + (l>>4)*8 + j  (j = 0..7, lane-contiguous 16B record).
__global__ __launch_bounds__(256) void wepack_kernel(
    const float* __restrict__ We, unsigned short* __restrict__ wf) {
  const int fl = blockIdx.x * 256 + threadIdx.x;   // 16 frags * 64 lanes
  if (fl >= 16 * 64) return;
  const int f = fl >> 6, lane = fl & 63;
  const int nt = f >> 1, kh = f & 1;
  const int n = nt * 16 + (lane & 15);
  const int kbase = kh * 32 + (lane >> 4) * 8;
#pragma unroll
  for (int j = 0; j < 8; ++j)
    wf[fl * 8 + j] = f2bf(We[(kbase + j) * HU + n]);
}

// K1: fused q/k/v projections. q fp32 (bq+be folded); k,v bf16 [n][128].
__global__ __launch_bounds__(128) void qkv_kernel(
    const float* __restrict__ x,
    const float* __restrict__ Wq, const float* __restrict__ bq,
    const float* __restrict__ Wk, const float* __restrict__ bk,
    const float* __restrict__ Wv, const float* __restrict__ bv,
    const float* __restrict__ be,
    float* __restrict__ q, unsigned short* __restrict__ kbf,
    unsigned short* __restrict__ vbf) {
  const int base = blockIdx.x * NPB;
  const int t = threadIdx.x;
  __shared__ float xs[NPB][D_IN];
  for (int j = 0; j < NPB; ++j)
    xs[j][t] = x[(long)(base + j) * D_IN + t];
  __syncthreads();
  float aq[NPB], ak[NPB], av[NPB];
  const float bqt = bq[t] + be[t], bkt = bk[t], bvt = bv[t];
#pragma unroll
  for (int j = 0; j < NPB; ++j) { aq[j] = bqt; ak[j] = bkt; av[j] = bvt; }
  for (int i = 0; i < D_IN; ++i) {
    const float wq = Wq[i * HU + t];
    const float wk = Wk[i * HU + t];
    const float wv = Wv[i * HU + t];
#pragma unroll
    for (int j = 0; j < NPB; ++j) {
      const float xi = xs[j][i];
      aq[j] += xi * wq; ak[j] += xi * wk; av[j] += xi * wv;
    }
  }
#pragma unroll
  for (int j = 0; j < NPB; ++j) {
    const long nn = base + j;
    q[nn * HU + t] = aq[j];
    kbf[nn * HU + t] = f2bf(ak[j]);
    vbf[nn * HU + t] = f2bf(av[j]);
  }
}

// K2: 64 edges per 256-thread block, TWO-PHASE over head-pairs.
//   Phase p (p=0,1): MFMA quarter-tiles nt=4p..4p+3 -> eh cols [64p,64p+64)
//   for this wave's 16 edges, staged in a 4 KB/wave LDS half-tile (REUSED
//   across phases; wave-local lgkm fences only — DS is in-order per wave,
//   no cross-wave coupling). Score phase p covers heads {2p,2p+1}, 2 lanes
//   per (edge,head) (one 16-col half each), combined with shfl_xor(p,1).
//   LDS: 32KB -> 16KB/block  => occupancy ceiling doubles. f32 precision kept.
__global__ __launch_bounds__(256) void score_kernel(
    const float* __restrict__ ef,
    const int* __restrict__ src, const int* __restrict__ dst,
    const float* __restrict__ q, const unsigned short* __restrict__ kbf,
    const s16x8* __restrict__ wf,
    float* __restrict__ scores) {
  __shared__ __align__(16) float ehs[4][16 * 64];   // 16 KB: 4 KB per wave
  const int t = threadIdx.x;
  const int w = t >> 6, l = t & 63;
  const long ebase = (long)blockIdx.x * 64;
  const int e = (int)(ebase + w * 16 + (l >> 2));
  const int s = src[e], d = dst[e];

  // A operand (shared by both phases): lane l holds ef[arow][k],
  // k = kh*32 + (l>>4)*8 + j
  const int arow = (int)(ebase + w * 16 + (l & 15));
  const fx4* ap = (const fx4*)(ef + (long)arow * ED_IN + (l >> 4) * 8);
  const fx4 a00 = __builtin_nontemporal_load(ap);
  const fx4 a01 = __builtin_nontemporal_load(ap + 1);
  const fx4 a10 = __builtin_nontemporal_load(ap + 8);
  const fx4 a11 = __builtin_nontemporal_load(ap + 9);
  s16x8 A0, A1;
  A0[0] = (short)f2bf(a00[0]); A0[1] = (short)f2bf(a00[1]);
  A0[2] = (short)f2bf(a00[2]); A0[3] = (short)f2bf(a00[3]);
  A0[4] = (short)f2bf(a01[0]); A0[5] = (short)f2bf(a01[1]);
  A0[6] = (short)f2bf(a01[2]); A0[7] = (short)f2bf(a01[3]);
  A1[0] = (short)f2bf(a10[0]); A1[1] = (short)f2bf(a10[1]);
  A1[2] = (short)f2bf(a10[2]); A1[3] = (short)f2bf(a10[3]);
  A1[4] = (short)f2bf(a11[0]); A1[5] = (short)f2bf(a11[1]);
  A1[6] = (short)f2bf(a11[2]); A1[7] = (short)f2bf(a11[3]);

  float* __restrict__ ehw = ehs[w];
  const int nb = l & 15, gbase = (l >> 4) * 4;
  const int rloc = l >> 2;                 // score-phase local edge row
  const int hl = (l >> 1) & 1, half = l & 1;
  const int swzr = (rloc & 7) << 4;

#pragma unroll
  for (int ph = 0; ph < 2; ++ph) {
    // 8 MFMAs: quarter-tiles nt = ph*4 .. ph*4+3, K=64 over two kh frags
    f32x4 acc[4];
#pragma unroll
    for (int ntl = 0; ntl < 4; ++ntl) acc[ntl] = (f32x4){0.f, 0.f, 0.f, 0.f};
#pragma unroll
    for (int ntl = 0; ntl < 4; ++ntl) {
      const int f = (ph * 4 + ntl) * 2;
      const s16x8 B0 = wf[(f + 0) * 64 + l];
      const s16x8 B1 = wf[(f + 1) * 64 + l];
      acc[ntl] = __builtin_amdgcn_mfma_f32_16x16x32_bf16(A0, B0, acc[ntl], 0, 0, 0);
      acc[ntl] = __builtin_amdgcn_mfma_f32_16x16x32_bf16(A1, B1, acc[ntl], 0, 0, 0);
    }

    // half-tile scatter: local row m = gbase+r, local col n = ntl*16+nb,
    // byte-in-row ^= (m&7)<<4 (same swizzle on read side below)
#pragma unroll
    for (int ntl = 0; ntl < 4; ++ntl) {
#pragma unroll
      for (int r = 0; r < 4; ++r) {
        const int m = gbase + r;
        const int b = (ntl * 16 + nb) * 4;
        ehw[(m * 256 + (b ^ ((m & 7) << 4))) >> 2] = acc[ntl][r];
      }
    }
    // wave-local: this wave's writes cover exactly the rows it reads below
    asm volatile("s_waitcnt lgkmcnt(0)" ::: "memory");
    __builtin_amdgcn_sched_barrier(0);

    // score partial: lane handles (edge rloc, head h=ph*2+hl), cols half*16..+15
    const int h = ph * 2 + hl;
    const char* ehp = (const char*)(ehw + rloc * 64);
    const int cb = (l & 3) * 64;   // = hl*128 + half*64 bytes within half-row
    const float4 e0 = *(const float4*)(ehp + ((cb + 0)  ^ swzr));
    const float4 e1 = *(const float4*)(ehp + ((cb + 16) ^ swzr));
    const float4 e2 = *(const float4*)(ehp + ((cb + 32) ^ swzr));
    const float4 e3 = *(const float4*)(ehp + ((cb + 48) ^ swzr));

    const float4* qp = (const float4*)(q + (long)s * HU + h * 32 + half * 16);
    const float4 q0 = qp[0], q1 = qp[1], q2 = qp[2], q3 = qp[3];
    const uint4* kp = (const uint4*)((const char*)kbf + (long)d * 256 + h * 64 + half * 32);
    const uint4 k0 = kp[0], k1 = kp[1];

    float p = dot8(f4add(q0, e0), f4add(q1, e1), k0)
            + dot8(f4add(q2, e2), f4add(q3, e3), k1);
    p += __shfl_xor(p, 1, 64);             // combine the two 16-col halves
    if (!half)
      __builtin_nontemporal_store(p, scores + (long)e * NH + h);

    // ensure phase-A reads retired before phase-B overwrites the half-tile
    asm volatile("s_waitcnt lgkmcnt(0)" ::: "memory");
    __builtin_amdgcn_sched_barrier(0);
  }
}

// K3: one WAVE per node (4 nodes per 256-thread block), barrier-free.
// Lane l: features 2l,2l+1 (head h=l>>4); softmax in 16-lane shuffle groups.
__global__ __launch_bounds__(256) void aggregate_kernel(
    const int* __restrict__ off, const int* __restrict__ dst,
    const float* __restrict__ scores, const unsigned* __restrict__ v2,
    const float* __restrict__ Wo, const float* __restrict__ bo,
    float* __restrict__ out) {
  const int wv = threadIdx.x >> 6, l = threadIdx.x & 63;
  const int n = blockIdx.x * 4 + wv;
  const int h = l >> 4, q16 = l & 15;
  __shared__ float att[4][HU];

  const int start = off[n], end = off[n + 1];
  float m = -INFINITY, lsum = 0.f, a0 = 0.f, a1 = 0.f;
  for (int cs = start; cs < end; cs += 16) {
    const int e = cs + q16;
    const bool live = (e < end);
    const float sc = live ? __builtin_nontemporal_load(scores + (long)e * NH + h)
                          : -INFINITY;
    const int dl = live ? dst[e] : 0;
    float mc = sc;
#pragma unroll
    for (int o = 8; o > 0; o >>= 1) mc = fmaxf(mc, __shfl_xor(mc, o, 16));
    const float nm = fmaxf(m, mc);          // finite: >=1 live edge per chunk
    const float corr = __expf(m - nm);      // 0 on first chunk
    const float w = __expf(sc - nm);        // 0 for dead lanes
    float ws = w;
#pragma unroll
    for (int o = 8; o > 0; o >>= 1) ws += __shfl_xor(ws, o, 16);
    lsum = lsum * corr + ws;
    a0 *= corr; a1 *= corr; m = nm;
    // fully unrolled: dead entries have w=0, dst=0 (harmless cached row-0 load)
#pragma unroll
    for (int j = 0; j < 16; ++j) {
      const float wj = __shfl(w, (l & 48) + j, 64);
      const int dj = __shfl(dl, (l & 48) + j, 64);
      const unsigned vr = v2[(long)dj * 64 + l];   // 256B coalesced row
      a0 += wj * bf_lo(vr);
      a1 += wj * bf_hi(vr);
    }
  }
  const float inv = (lsum > 0.f) ? 1.f / lsum : 0.f;
  att[wv][2 * l] = a0 * inv;
  att[wv][2 * l + 1] = a1 * inv;
  // wave-synchronous: same wave wrote these LDS entries, no barrier needed
  const int o = l & 31, half = l >> 5;
  float po = 0.f;
#pragma unroll
  for (int f = 0; f < 64; ++f)
    po += att[wv][half * 64 + f] * Wo[(half * 64 + f) * UD + o];
  po += __shfl_down(po, 32, 64);
  if (l < 32) out[(long)n * UD + l] = fmaxf(po + bo[l], 0.f);
}

extern "C" void kernel_launch(void* const* d_in, const int* in_sizes, int n_in,
                              void* d_out, int out_size, void* d_ws, size_t ws_size,
                              hipStream_t stream) {
  const float* x  = (const float*)d_in[0];
  const int*   ei = (const int*)d_in[1];
  const float* ef = (const float*)d_in[2];
  const float* Wq = (const float*)d_in[3];
  const float* bq = (const float*)d_in[4];
  const float* Wk = (const float*)d_in[5];
  const float* bk = (const float*)d_in[6];
  const float* Wv = (const float*)d_in[7];
  const float* bv = (const float*)d_in[8];
  const float* We = (const float*)d_in[9];
  const float* be = (const float*)d_in[10];
  const float* Wo = (const float*)d_in[11];
  const float* bo = (const float*)d_in[12];
  float* out = (float*)d_out;

  const int* src = ei;             // edge_index[0]
  const int* dst = ei + N_EDGES;   // edge_index[1]

  // ws: q fp32 [N*128] | kbf [N*128] | vbf [N*128] | scores [E*4] | off | wf
  float* q = (float*)d_ws;
  unsigned short* kbf = (unsigned short*)(q + (long)N_NODES * HU);
  unsigned short* vbf = kbf + (long)N_NODES * HU;
  float* scores = (float*)(vbf + (long)N_NODES * HU);
  int* off = (int*)(scores + (long)N_EDGES * NH);
  unsigned short* wf = (unsigned short*)(((uintptr_t)(off + N_NODES + 1) + 15)
                                         & ~(uintptr_t)15);

  offsets_kernel<<<(N_EDGES + 255) / 256, 256, 0, stream>>>(src, off);
  wepack_kernel<<<4, 256, 0, stream>>>(We, wf);
  qkv_kernel<<<N_NODES / NPB, 128, 0, stream>>>(x, Wq, bq, Wk, bk, Wv, bv, be,
                                                q, kbf, vbf);
  score_kernel<<<N_EDGES / 64, 256, 0, stream>>>(ef, src, dst, q, kbf,
                                                 (const s16x8*)wf, scores);
  aggregate_kernel<<<N_NODES / 4, 256, 0, stream>>>(off, dst, scores,
                                                    (const unsigned*)vbf, Wo, bo, out);
}

// Round 6
// 459.180 us; speedup vs baseline: 1.3583x; 1.0750x over previous
//
#include <hip/hip_runtime.h>
#include <math.h>

#define N_NODES 50000
#define N_EDGES 800000
#define D_IN    128
#define ED_IN   64
#define HU      128   // H*U
#define NH      4
#define UD      32

typedef float fx4 __attribute__((ext_vector_type(4)));
typedef short s16x8 __attribute__((ext_vector_type(8)));
typedef float f32x4 __attribute__((ext_vector_type(4)));

static __device__ __forceinline__ unsigned short f2bf(float f) {
  unsigned u = __float_as_uint(f);
  unsigned r = (u + 0x7FFFu + ((u >> 16) & 1u)) >> 16;
  return (unsigned short)r;
}
static __device__ __forceinline__ float bf_lo(unsigned u) {
  return __uint_as_float(u << 16);
}
static __device__ __forceinline__ float bf_hi(unsigned u) {
  return __uint_as_float(u & 0xFFFF0000u);
}
static __device__ __forceinline__ float bf2f(unsigned short h) {
  return __uint_as_float(((unsigned)h) << 16);
}
// 8-element dot: fp32 a0|a1 against 8 bf16 packed in uint4
static __device__ __forceinline__ float dot8(float4 a0, float4 a1, uint4 kk) {
  return a0.x * bf_lo(kk.x) + a0.y * bf_hi(kk.x)
       + a0.z * bf_lo(kk.y) + a0.w * bf_hi(kk.y)
       + a1.x * bf_lo(kk.z) + a1.y * bf_hi(kk.z)
       + a1.z * bf_lo(kk.w) + a1.w * bf_hi(kk.w);
}
static __device__ __forceinline__ float4 f4add(float4 a, float4 b) {
  return make_float4(a.x + b.x, a.y + b.y, a.z + b.z, a.w + b.w);
}

// K0: segment offsets from sorted src. off[n] = lower_bound(src, n); off[N] = E.
__global__ __launch_bounds__(256) void offsets_kernel(
    const int* __restrict__ src, int* __restrict__ off) {
  const int e = blockIdx.x * 256 + threadIdx.x;
  if (e >= N_EDGES) return;
  const int s = src[e];
  const int prev = (e == 0) ? -1 : src[e - 1];
  for (int n = prev + 1; n <= s; ++n) off[n] = e;
  if (e == N_EDGES - 1)
    for (int n = s + 1; n <= N_NODES; ++n) off[n] = N_EDGES;
}

// K0b: pack We (fp32 [64][128]) into bf16 MFMA B-fragments for 16x16x32:
// frag f = nt*2+kh, lane l holds B[k][n] for n = nt*16+(l&15),
// k = kh*32 + (l>>4)*8 + j  (j = 0..7, lane-contiguous 16B record).
__global__ __launch_bounds__(256) void wepack_kernel(
    const float* __restrict__ We, unsigned short* __restrict__ wf) {
  const int fl = blockIdx.x * 256 + threadIdx.x;   // 16 frags * 64 lanes
  if (fl >= 16 * 64) return;
  const int f = fl >> 6, lane = fl & 63;
  const int nt = f >> 1, kh = f & 1;
  const int n = nt * 16 + (lane & 15);
  const int kbase = kh * 32 + (lane >> 4) * 8;
#pragma unroll
  for (int j = 0; j < 8; ++j)
    wf[fl * 8 + j] = f2bf(We[(kbase + j) * HU + n]);
}

// K0c: pack Wq|Wk|Wv (fp32 [128][128] each) into hi/lo bf16 MFMA B-frags.
// frag f = proj*32 + nt*4 + kf; lane l holds W[k][n], n = nt*16+(l&15),
// k = kf*32+(l>>4)*8+j. hi at [fl*8+j], lo at [+96*64*8].
__global__ __launch_bounds__(256) void wqkvpack_kernel(
    const float* __restrict__ Wq, const float* __restrict__ Wk,
    const float* __restrict__ Wv, unsigned short* __restrict__ wqkv) {
  const int fl = blockIdx.x * 256 + threadIdx.x;   // 96 frags * 64 lanes
  if (fl >= 96 * 64) return;
  const int f = fl >> 6, lane = fl & 63;
  const int proj = f >> 5, nt = (f >> 2) & 7, kf = f & 3;
  const float* W = proj == 0 ? Wq : (proj == 1 ? Wk : Wv);
  const int n = nt * 16 + (lane & 15);
  const int kb = kf * 32 + (lane >> 4) * 8;
#pragma unroll
  for (int j = 0; j < 8; ++j) {
    const float v = W[(kb + j) * HU + n];
    const unsigned short h = f2bf(v);
    wqkv[fl * 8 + j] = h;
    wqkv[96 * 64 * 8 + fl * 8 + j] = f2bf(v - bf2f(h));
  }
}

// K1: q/k/v projections via MFMA with 3-term hi/lo split (fp32-grade):
//   acc = xh@Wh + xl@Wh + xh@Wl   (xl@Wl ~ 2^-18, dropped)
// Block = 16 nodes, 4 waves; wave w computes tiles tt = w*6..w*6+5,
// tt -> (proj = tt>>3, nt = tt&7). No LDS. q fp32 (bq+be folded); k,v bf16.
__global__ __launch_bounds__(256) void qkv_kernel(
    const float* __restrict__ x, const s16x8* __restrict__ wqkv,
    const float* __restrict__ bq, const float* __restrict__ be,
    const float* __restrict__ bk, const float* __restrict__ bv,
    float* __restrict__ q, unsigned short* __restrict__ kbf,
    unsigned short* __restrict__ vbf) {
  const int base = blockIdx.x * 16;
  const int t = threadIdx.x;
  const int w = t >> 6, l = t & 63;

  // A fragments: lane l row = base+(l&15), k = kf*32+(l>>4)*8+j
  const float* xr = x + (long)(base + (l & 15)) * D_IN + (l >> 4) * 8;
  s16x8 Ah[4], Al[4];
#pragma unroll
  for (int kf = 0; kf < 4; ++kf) {
    const fx4 c0 = *(const fx4*)(xr + kf * 32);
    const fx4 c1 = *(const fx4*)(xr + kf * 32 + 4);
#pragma unroll
    for (int j = 0; j < 4; ++j) {
      const unsigned short h0 = f2bf(c0[j]);
      const unsigned short h1 = f2bf(c1[j]);
      Ah[kf][j] = (short)h0;     Al[kf][j] = (short)f2bf(c0[j] - bf2f(h0));
      Ah[kf][4 + j] = (short)h1; Al[kf][4 + j] = (short)f2bf(c1[j] - bf2f(h1));
    }
  }

#pragma unroll
  for (int i = 0; i < 6; ++i) {
    const int tt = w * 6 + i;
    const int proj = tt >> 3, nt = tt & 7;
    const int col = nt * 16 + (l & 15);
    f32x4 acc = (f32x4){0.f, 0.f, 0.f, 0.f};
#pragma unroll
    for (int kf = 0; kf < 4; ++kf) {
      const int fr = proj * 32 + nt * 4 + kf;
      const s16x8 Bh = wqkv[fr * 64 + l];
      const s16x8 Bl = wqkv[96 * 64 + fr * 64 + l];
      acc = __builtin_amdgcn_mfma_f32_16x16x32_bf16(Ah[kf], Bh, acc, 0, 0, 0);
      acc = __builtin_amdgcn_mfma_f32_16x16x32_bf16(Al[kf], Bh, acc, 0, 0, 0);
      acc = __builtin_amdgcn_mfma_f32_16x16x32_bf16(Ah[kf], Bl, acc, 0, 0, 0);
    }
    float bias;
    if (proj == 0)      bias = bq[col] + be[col];
    else if (proj == 1) bias = bk[col];
    else                bias = bv[col];
#pragma unroll
    for (int r = 0; r < 4; ++r) {
      const long node = base + (l >> 4) * 4 + r;
      const float val = acc[r] + bias;
      if (proj == 0)      q[node * HU + col] = val;
      else if (proj == 1) kbf[node * HU + col] = f2bf(val);
      else                vbf[node * HU + col] = f2bf(val);
    }
  }
}

// K2: 64 edges per 256-thread block, TWO-PHASE over head-pairs.
//   Phase p (p=0,1): MFMA quarter-tiles nt=4p..4p+3 -> eh cols [64p,64p+64)
//   for this wave's 16 edges, staged in a 4 KB/wave LDS half-tile (REUSED
//   across phases; wave-local lgkm fences only). Score phase p covers heads
//   {2p,2p+1}, 2 lanes per (edge,head), combined with shfl_xor(p,1).
__global__ __launch_bounds__(256) void score_kernel(
    const float* __restrict__ ef,
    const int* __restrict__ src, const int* __restrict__ dst,
    const float* __restrict__ q, const unsigned short* __restrict__ kbf,
    const s16x8* __restrict__ wf,
    float* __restrict__ scores) {
  __shared__ __align__(16) float ehs[4][16 * 64];   // 16 KB: 4 KB per wave
  const int t = threadIdx.x;
  const int w = t >> 6, l = t & 63;
  const long ebase = (long)blockIdx.x * 64;
  const int e = (int)(ebase + w * 16 + (l >> 2));
  const int s = src[e], d = dst[e];

  // A operand (shared by both phases): lane l holds ef[arow][k],
  // k = kh*32 + (l>>4)*8 + j
  const int arow = (int)(ebase + w * 16 + (l & 15));
  const fx4* ap = (const fx4*)(ef + (long)arow * ED_IN + (l >> 4) * 8);
  const fx4 a00 = __builtin_nontemporal_load(ap);
  const fx4 a01 = __builtin_nontemporal_load(ap + 1);
  const fx4 a10 = __builtin_nontemporal_load(ap + 8);
  const fx4 a11 = __builtin_nontemporal_load(ap + 9);
  s16x8 A0, A1;
  A0[0] = (short)f2bf(a00[0]); A0[1] = (short)f2bf(a00[1]);
  A0[2] = (short)f2bf(a00[2]); A0[3] = (short)f2bf(a00[3]);
  A0[4] = (short)f2bf(a01[0]); A0[5] = (short)f2bf(a01[1]);
  A0[6] = (short)f2bf(a01[2]); A0[7] = (short)f2bf(a01[3]);
  A1[0] = (short)f2bf(a10[0]); A1[1] = (short)f2bf(a10[1]);
  A1[2] = (short)f2bf(a10[2]); A1[3] = (short)f2bf(a10[3]);
  A1[4] = (short)f2bf(a11[0]); A1[5] = (short)f2bf(a11[1]);
  A1[6] = (short)f2bf(a11[2]); A1[7] = (short)f2bf(a11[3]);

  float* __restrict__ ehw = ehs[w];
  const int nb = l & 15, gbase = (l >> 4) * 4;
  const int rloc = l >> 2;                 // score-phase local edge row
  const int hl = (l >> 1) & 1, half = l & 1;
  const int swzr = (rloc & 7) << 4;

#pragma unroll
  for (int ph = 0; ph < 2; ++ph) {
    // 8 MFMAs: quarter-tiles nt = ph*4 .. ph*4+3, K=64 over two kh frags
    f32x4 acc[4];
#pragma unroll
    for (int ntl = 0; ntl < 4; ++ntl) acc[ntl] = (f32x4){0.f, 0.f, 0.f, 0.f};
#pragma unroll
    for (int ntl = 0; ntl < 4; ++ntl) {
      const int f = (ph * 4 + ntl) * 2;
      const s16x8 B0 = wf[(f + 0) * 64 + l];
      const s16x8 B1 = wf[(f + 1) * 64 + l];
      acc[ntl] = __builtin_amdgcn_mfma_f32_16x16x32_bf16(A0, B0, acc[ntl], 0, 0, 0);
      acc[ntl] = __builtin_amdgcn_mfma_f32_16x16x32_bf16(A1, B1, acc[ntl], 0, 0, 0);
    }

    // half-tile scatter: local row m = gbase+r, local col n = ntl*16+nb,
    // byte-in-row ^= (m&7)<<4 (same swizzle on read side below)
#pragma unroll
    for (int ntl = 0; ntl < 4; ++ntl) {
#pragma unroll
      for (int r = 0; r < 4; ++r) {
        const int m = gbase + r;
        const int b = (ntl * 16 + nb) * 4;
        ehw[(m * 256 + (b ^ ((m & 7) << 4))) >> 2] = acc[ntl][r];
      }
    }
    // wave-local: this wave's writes cover exactly the rows it reads below
    asm volatile("s_waitcnt lgkmcnt(0)" ::: "memory");
    __builtin_amdgcn_sched_barrier(0);

    // score partial: lane handles (edge rloc, head h=ph*2+hl), cols half*16..+15
    const int h = ph * 2 + hl;
    const char* ehp = (const char*)(ehw + rloc * 64);
    const int cb = (l & 3) * 64;   // = hl*128 + half*64 bytes within half-row
    const float4 e0 = *(const float4*)(ehp + ((cb + 0)  ^ swzr));
    const float4 e1 = *(const float4*)(ehp + ((cb + 16) ^ swzr));
    const float4 e2 = *(const float4*)(ehp + ((cb + 32) ^ swzr));
    const float4 e3 = *(const float4*)(ehp + ((cb + 48) ^ swzr));

    const float4* qp = (const float4*)(q + (long)s * HU + h * 32 + half * 16);
    const float4 q0 = qp[0], q1 = qp[1], q2 = qp[2], q3 = qp[3];
    const uint4* kp = (const uint4*)((const char*)kbf + (long)d * 256 + h * 64 + half * 32);
    const uint4 k0 = kp[0], k1 = kp[1];

    float p = dot8(f4add(q0, e0), f4add(q1, e1), k0)
            + dot8(f4add(q2, e2), f4add(q3, e3), k1);
    p += __shfl_xor(p, 1, 64);             // combine the two 16-col halves
    if (!half)
      __builtin_nontemporal_store(p, scores + (long)e * NH + h);

    // ensure phase-A reads retired before phase-B overwrites the half-tile
    asm volatile("s_waitcnt lgkmcnt(0)" ::: "memory");
    __builtin_amdgcn_sched_barrier(0);
  }
}

// K3: one WAVE per node (4 nodes per 256-thread block).
// Lane l: features 2l,2l+1 (head h=l>>4); softmax in 16-lane shuffle groups.
// dst index per edge is wave-uniform -> readlane (SALU) instead of shfl (DS);
// Wo staged block-wide in LDS (one barrier at start).
__global__ __launch_bounds__(256) void aggregate_kernel(
    const int* __restrict__ off, const int* __restrict__ dst,
    const float* __restrict__ scores, const unsigned* __restrict__ v2,
    const float* __restrict__ Wo, const float* __restrict__ bo,
    float* __restrict__ out) {
  const int wv = threadIdx.x >> 6, l = threadIdx.x & 63;
  const int n = blockIdx.x * 4 + wv;
  const int h = l >> 4, q16 = l & 15;
  __shared__ float att[4][HU];
  __shared__ __align__(16) float wos[HU * UD];   // 16 KB

  // stage Wo once per block (coalesced float4), shared by all 4 waves
  {
    const fx4* wop = (const fx4*)Wo;
    fx4* wosp = (fx4*)wos;
#pragma unroll
    for (int r = 0; r < 4; ++r)
      wosp[threadIdx.x + 256 * r] = wop[threadIdx.x + 256 * r];
  }
  __syncthreads();

  const int start = off[n], end = off[n + 1];
  float m = -INFINITY, lsum = 0.f, a0 = 0.f, a1 = 0.f;
  for (int cs = start; cs < end; cs += 16) {
    const int e = cs + q16;
    const bool live = (e < end);
    const float sc = live ? __builtin_nontemporal_load(scores + (long)e * NH + h)
                          : -INFINITY;
    const int dl = live ? dst[e] : 0;
    float mc = sc;
#pragma unroll
    for (int o = 8; o > 0; o >>= 1) mc = fmaxf(mc, __shfl_xor(mc, o, 16));
    const float nm = fmaxf(m, mc);          // finite: >=1 live edge per chunk
    const float corr = __expf(m - nm);      // 0 on first chunk
    const float w = __expf(sc - nm);        // 0 for dead lanes
    float ws = w;
#pragma unroll
    for (int o = 8; o > 0; o >>= 1) ws += __shfl_xor(ws, o, 16);
    lsum = lsum * corr + ws;
    a0 *= corr; a1 *= corr; m = nm;
    // dead entries have w=0, dj=0 (harmless cached row-0 load).
    // dj is wave-uniform (one wave = one node): readlane -> SGPR base,
    // frees the DS pipe; only the per-head weight needs a shuffle.
#pragma unroll
    for (int j = 0; j < 16; ++j) {
      const float wj = __shfl(w, (l & 48) + j, 64);
      const int dj = __builtin_amdgcn_readlane(dl, j);
      const unsigned vr = v2[(long)dj * 64 + l];   // 256B coalesced row
      a0 += wj * bf_lo(vr);
      a1 += wj * bf_hi(vr);
    }
  }
  const float inv = (lsum > 0.f) ? 1.f / lsum : 0.f;
  att[wv][2 * l] = a0 * inv;
  att[wv][2 * l + 1] = a1 * inv;
  // wave-synchronous: same wave wrote these LDS entries, no barrier needed
  const int o = l & 31, half = l >> 5;
  float po = 0.f;
#pragma unroll
  for (int f = 0; f < 64; ++f)
    po += att[wv][half * 64 + f] * wos[(half * 64 + f) * UD + o];
  po += __shfl_down(po, 32, 64);
  if (l < 32) out[(long)n * UD + l] = fmaxf(po + bo[l], 0.f);
}

extern "C" void kernel_launch(void* const* d_in, const int* in_sizes, int n_in,
                              void* d_out, int out_size, void* d_ws, size_t ws_size,
                              hipStream_t stream) {
  const float* x  = (const float*)d_in[0];
  const int*   ei = (const int*)d_in[1];
  const float* ef = (const float*)d_in[2];
  const float* Wq = (const float*)d_in[3];
  const float* bq = (const float*)d_in[4];
  const float* Wk = (const float*)d_in[5];
  const float* bk = (const float*)d_in[6];
  const float* Wv = (const float*)d_in[7];
  const float* bv = (const float*)d_in[8];
  const float* We = (const float*)d_in[9];
  const float* be = (const float*)d_in[10];
  const float* Wo = (const float*)d_in[11];
  const float* bo = (const float*)d_in[12];
  float* out = (float*)d_out;

  const int* src = ei;             // edge_index[0]
  const int* dst = ei + N_EDGES;   // edge_index[1]

  // ws: q fp32 [N*128] | kbf [N*128] | vbf [N*128] | scores [E*4] | off |
  //     wf (16 frags) | wqkv (96 frags hi + 96 lo)
  float* q = (float*)d_ws;
  unsigned short* kbf = (unsigned short*)(q + (long)N_NODES * HU);
  unsigned short* vbf = kbf + (long)N_NODES * HU;
  float* scores = (float*)(vbf + (long)N_NODES * HU);
  int* off = (int*)(scores + (long)N_EDGES * NH);
  unsigned short* wf = (unsigned short*)(((uintptr_t)(off + N_NODES + 1) + 15)
                                         & ~(uintptr_t)15);
  unsigned short* wqkv = wf + 16 * 64 * 8;   // 16 KB after wf, stays 16B-aligned

  offsets_kernel<<<(N_EDGES + 255) / 256, 256, 0, stream>>>(src, off);
  wepack_kernel<<<4, 256, 0, stream>>>(We, wf);
  wqkvpack_kernel<<<24, 256, 0, stream>>>(Wq, Wk, Wv, wqkv);
  qkv_kernel<<<N_NODES / 16, 256, 0, stream>>>(x, (const s16x8*)wqkv,
                                               bq, be, bk, bv, q, kbf, vbf);
  score_kernel<<<N_EDGES / 64, 256, 0, stream>>>(ef, src, dst, q, kbf,
                                                 (const s16x8*)wf, scores);
  aggregate_kernel<<<N_NODES / 4, 256, 0, stream>>>(off, dst, scores,
                                                    (const unsigned*)vbf, Wo, bo, out);
}